// Round 6
// baseline (195.699 us; speedup 1.0000x reference)
//
#include <hip/hip_runtime.h>

#define Bn 128
#define Hn 28
#define Wn 28
#define Cn 512
#define Pn (Hn * Wn)       // 784 spatial positions
#define NCH 8              // batch chunks (pipeline stages)
#define CB (Bn / NCH)      // 16 batches per chunk
#define SCH 28             // spatial sub-chunks for argmax
#define PCH (Pn / SCH)     // 28 positions per sub-chunk
#define ARGB ((CB / 2) * SCH)  // 224 argmax blocks per chunk (2 b per block)
#define MSKB (CB * 14)         // 224 mask blocks per chunk
#define PPB 56             // p per mask block (784 = 14*56)
#define PPT 28             // p per mask thread (half-block)

// Native vector types for __builtin_nontemporal_{load,store} (HIP's float4
// class is rejected by the builtins; these are layout-identical).
typedef float f4 __attribute__((ext_vector_type(4)));

__device__ __forceinline__ void nt_store4(float* p, float a, float b, float c, float d) {
    f4 v = {a, b, c, d};
    __builtin_nontemporal_store(v, reinterpret_cast<f4*>(p));
}
__device__ __forceinline__ f4 nt_load4(const float* p) {
    return __builtin_nontemporal_load(reinterpret_cast<const f4*>(p));
}

// ---------------------------------------------------------------------------
// Pipelined kernel: one dispatch contains two block roles.
//   blocks [0, nArg)        : ARGMAX role on chunk k   -> part[k&1]
//   blocks [nArg, nArg+msk) : MASK   role on chunk k-1 <- part[(k-1)&1]
// Chunk k's x (25.7 MB) is streamed by the argmax role; one dispatch later the
// mask role re-reads it from the 256 MB L3 (working set ~55 MB) with NT loads
// (last use), and NT-stores all three outputs so the write streams don't evict
// the incoming chunk. part[] is double-buffered: no aliasing between adjacent
// dispatches; stream order provides the cross-dispatch dependency.
// ---------------------------------------------------------------------------
__global__ __launch_bounds__(256) void pipe(const float* __restrict__ x,
                                            const float* __restrict__ tp,
                                            float* __restrict__ o0,
                                            float* __restrict__ o1,
                                            float* __restrict__ o2,
                                            uint2* __restrict__ part,
                                            int k, int nArg) {
    __shared__ int sidx[Cn];   // combined argmax indices for the mask role's b

    if ((int)blockIdx.x < nArg) {
        // ---------------- ARGMAX role: chunk k ----------------
        int blk = blockIdx.x;
        int s  = blk % SCH;
        int bp = blk / SCH;                       // 0..CB/2-1
        int bl = bp * 2 + (threadIdx.x >> 7);     // local batch 0..CB-1
        int b  = k * CB + bl;
        int c0 = (threadIdx.x & 127) * 4;

        size_t base = (size_t)b * Pn * Cn + c0;
        int p0 = s * PCH;

        float b0 = -INFINITY, b1 = -INFINITY, b2 = -INFINITY, b3 = -INFINITY;
        int i0 = p0, i1 = p0, i2 = p0, i3 = p0;
#pragma unroll 7
        for (int i = 0; i < PCH; ++i) {
            float4 v = *reinterpret_cast<const float4*>(x + base + (size_t)(p0 + i) * Cn);
            if (v.x > b0) { b0 = v.x; i0 = p0 + i; }
            if (v.y > b1) { b1 = v.y; i1 = p0 + i; }
            if (v.z > b2) { b2 = v.z; i2 = p0 + i; }
            if (v.w > b3) { b3 = v.w; i3 = p0 + i; }
        }
        uint2* o = part + (((size_t)(k & 1) * SCH + s) * CB + bl) * Cn + c0;
        o[0] = make_uint2(__float_as_uint(b0), (unsigned)i0);
        o[1] = make_uint2(__float_as_uint(b1), (unsigned)i1);
        o[2] = make_uint2(__float_as_uint(b2), (unsigned)i2);
        o[3] = make_uint2(__float_as_uint(b3), (unsigned)i3);
        return;
    }

    // ---------------- MASK role: chunk k-1 ----------------
    int blk = blockIdx.x - nArg;
    int pc = blk % 14;
    int bl = blk / 14;                 // local batch 0..CB-1
    int b  = (k - 1) * CB + bl;
    int t  = threadIdx.x;

    // Inline combine: threads 0..127 each fold 28 partials for 4 c's into LDS.
    // Ascending s with strict > preserves np.argmax first-max tie-breaking.
    if (t < 128) {
        int c0 = t * 4;
        const uint2* pp = part + ((size_t)((k - 1) & 1) * SCH * CB + bl) * Cn + c0;
        float v0 = -INFINITY, v1 = -INFINITY, v2 = -INFINITY, v3 = -INFINITY;
        int j0 = 0, j1 = 0, j2 = 0, j3 = 0;
#pragma unroll
        for (int s = 0; s < SCH; ++s) {
            const uint2* q = pp + (size_t)s * (CB * Cn);
            uint4 a = *reinterpret_cast<const uint4*>(q);      // (val0,idx0,val1,idx1)
            uint4 c = *reinterpret_cast<const uint4*>(q + 2);  // (val2,idx2,val3,idx3)
            float f0 = __uint_as_float(a.x), f1 = __uint_as_float(a.z);
            float f2 = __uint_as_float(c.x), f3 = __uint_as_float(c.z);
            if (f0 > v0) { v0 = f0; j0 = (int)a.y; }
            if (f1 > v1) { v1 = f1; j1 = (int)a.w; }
            if (f2 > v2) { v2 = f2; j2 = (int)c.y; }
            if (f3 > v3) { v3 = f3; j3 = (int)c.w; }
        }
        sidx[c0 + 0] = j0;
        sidx[c0 + 1] = j1;
        sidx[c0 + 2] = j2;
        sidx[c0 + 3] = j3;
    }
    __syncthreads();

    int ci = t & 127;
    int c0 = ci * 4;
    int ph = t >> 7;
    int p0 = pc * PPB + ph * PPT;

    int4 iv = *reinterpret_cast<const int4*>(sidx + c0);
    const float* t0p = tp + (size_t)iv.x * Pn;
    const float* t1p = tp + (size_t)iv.y * Pn;
    const float* t2p = tp + (size_t)iv.z * Pn;
    const float* t3p = tp + (size_t)iv.w * Pn;

    size_t xbase = (size_t)b * Pn * Cn + c0;

#pragma unroll
    for (int j = 0; j < PPT; j += 4) {
        int p = p0 + j;
        // 4 template rows, 4 consecutive p each (per-lane sequential, L2/L3-hot)
        float4 ta = *reinterpret_cast<const float4*>(t0p + p);
        float4 tb = *reinterpret_cast<const float4*>(t1p + p);
        float4 tc = *reinterpret_cast<const float4*>(t2p + p);
        float4 td = *reinterpret_cast<const float4*>(t3p + p);
        // x re-read: L3-resident (streamed one dispatch ago); NT = last use.
        f4 x0 = nt_load4(x + xbase + (size_t)(p + 0) * Cn);
        f4 x1 = nt_load4(x + xbase + (size_t)(p + 1) * Cn);
        f4 x2 = nt_load4(x + xbase + (size_t)(p + 2) * Cn);
        f4 x3 = nt_load4(x + xbase + (size_t)(p + 3) * Cn);

        size_t q0 = xbase + (size_t)(p + 0) * Cn;
        size_t q1 = xbase + (size_t)(p + 1) * Cn;
        size_t q2 = xbase + (size_t)(p + 2) * Cn;
        size_t q3 = xbase + (size_t)(p + 3) * Cn;

        // o1 = x copy
        nt_store4(o1 + q0, x0.x, x0.y, x0.z, x0.w);
        nt_store4(o1 + q1, x1.x, x1.y, x1.z, x1.w);
        nt_store4(o1 + q2, x2.x, x2.y, x2.z, x2.w);
        nt_store4(o1 + q3, x3.x, x3.y, x3.z, x3.w);
        // o0 = relu(x * t)
        nt_store4(o0 + q0, fmaxf(x0.x * ta.x, 0.f), fmaxf(x0.y * tb.x, 0.f),
                           fmaxf(x0.z * tc.x, 0.f), fmaxf(x0.w * td.x, 0.f));
        nt_store4(o0 + q1, fmaxf(x1.x * ta.y, 0.f), fmaxf(x1.y * tb.y, 0.f),
                           fmaxf(x1.z * tc.y, 0.f), fmaxf(x1.w * td.y, 0.f));
        nt_store4(o0 + q2, fmaxf(x2.x * ta.z, 0.f), fmaxf(x2.y * tb.z, 0.f),
                           fmaxf(x2.z * tc.z, 0.f), fmaxf(x2.w * td.z, 0.f));
        nt_store4(o0 + q3, fmaxf(x3.x * ta.w, 0.f), fmaxf(x3.y * tb.w, 0.f),
                           fmaxf(x3.z * tc.w, 0.f), fmaxf(x3.w * td.w, 0.f));
        // o2 = templates
        nt_store4(o2 + q0, ta.x, tb.x, tc.x, td.x);
        nt_store4(o2 + q1, ta.y, tb.y, tc.y, td.y);
        nt_store4(o2 + q2, ta.z, tb.z, tc.z, td.z);
        nt_store4(o2 + q3, ta.w, tb.w, tc.w, td.w);
    }
}

extern "C" void kernel_launch(void* const* d_in, const int* in_sizes, int n_in,
                              void* d_out, int out_size, void* d_ws, size_t ws_size,
                              hipStream_t stream) {
    const float* x  = (const float*)d_in[0];   // [B,H,W,C] fp32
    const float* tp = (const float*)d_in[1];   // [H,W,H,W] fp32

    const size_t N = (size_t)Bn * Pn * Cn;
    float* o0 = (float*)d_out;                 // masked
    float* o1 = o0 + N;                        // x copy
    float* o2 = o0 + 2 * N;                    // templates

    // Workspace: double-buffered partials [2][SCH][CB][Cn] uint2 = 3.67 MB.
    uint2* part = (uint2*)d_ws;

    // 9-stage software pipeline: dispatch k = argmax(chunk k) + mask(chunk k-1).
    for (int k = 0; k <= NCH; ++k) {
        int nArg  = (k < NCH) ? ARGB : 0;
        int nMask = (k > 0) ? MSKB : 0;
        pipe<<<nArg + nMask, 256, 0, stream>>>(x, tp, o0, o1, o2, part, k, nArg);
    }
}